// Round 2
// baseline (1312.067 us; speedup 1.0000x reference)
//
#include <hip/hip_runtime.h>
#include <hip/hip_bf16.h>

#define B_    4
#define C_    256
#define HW    4096
#define INTER 128
#define N_    2048   // seq len after the (b,256,2048) reinterpretation

typedef unsigned short u16;

__device__ __forceinline__ float bf2f(u16 u) {
    return __uint_as_float(((unsigned)u) << 16);
}
__device__ __forceinline__ u16 f2bf(float f) {
    unsigned x = __float_as_uint(f);
    x += 0x7fff + ((x >> 16) & 1);   // round to nearest even
    return (u16)(x >> 16);
}

// ---------------------------------------------------------------------------
// Kernel 1: fused 1x1 convs (phi, theta, g -> bf16) + W_AB residual (f32) to out.
// ---------------------------------------------------------------------------
__global__ __launch_bounds__(256) void convs_kernel(
    const float* __restrict__ A, const float* __restrict__ Bx,
    const float* __restrict__ Wphi, const float* __restrict__ Wtheta,
    const float* __restrict__ Wg, const float* __restrict__ Wab,
    u16* __restrict__ phi, u16* __restrict__ theta,
    u16* __restrict__ g, float* __restrict__ out)
{
    const int p  = blockIdx.x * 256 + threadIdx.x;   // 0..4095
    const int og = blockIdx.y;                       // 0..15
    const int b  = blockIdx.z;
    const float* Ab = A  + (size_t)b * C_ * HW;
    const float* Bb = Bx + (size_t)b * C_ * HW;

    float accP[8]  = {};
    float accT[8]  = {};
    float accG[8]  = {};
    float accO[16] = {};

    for (int c = 0; c < C_; ++c) {
        const float a  = Ab[(size_t)c * HW + p];
        const float bb = Bb[(size_t)c * HW + p];
        #pragma unroll
        for (int j = 0; j < 8; ++j) {
            const int o = og * 8 + j;
            accP[j] = fmaf(Wphi[o * C_ + c],          a,  accP[j]);
            accT[j] = fmaf(Wtheta[o * C_ + c],        bb, accT[j]);
            accG[j] = fmaf(Wg[o * 2 * C_ + c],        a,  accG[j]);
            accG[j] = fmaf(Wg[o * 2 * C_ + C_ + c],   bb, accG[j]);
        }
        #pragma unroll
        for (int j = 0; j < 16; ++j) {
            const int o2 = og * 16 + j;
            accO[j] = fmaf(Wab[o2 * 2 * C_ + c],      a,  accO[j]);
            accO[j] = fmaf(Wab[o2 * 2 * C_ + C_ + c], bb, accO[j]);
        }
    }

    u16* pb = phi   + (size_t)b * INTER * HW;
    u16* tb = theta + (size_t)b * INTER * HW;
    u16* gb = g     + (size_t)b * INTER * HW;
    #pragma unroll
    for (int j = 0; j < 8; ++j) {
        pb[(size_t)(og * 8 + j) * HW + p] = f2bf(accP[j]);
        tb[(size_t)(og * 8 + j) * HW + p] = f2bf(accT[j]);
        gb[(size_t)(og * 8 + j) * HW + p] = f2bf(accG[j]);
    }
    float* ob = out + (size_t)b * C_ * HW;
    #pragma unroll
    for (int j = 0; j < 16; ++j)
        ob[(size_t)(og * 16 + j) * HW + p] = accO[j];
}

// ---------------------------------------------------------------------------
// Pass A: partial row sums of exp(S).  S[m][n] = sum_c phi[c][m]*theta[c][n].
// Block: 64 m-rows x 512 n-range (quarter nq). rsp[nq][b][m] = partial sum.
// ---------------------------------------------------------------------------
__global__ __launch_bounds__(256) void passA_rowsum(
    const u16* __restrict__ phi, const u16* __restrict__ theta,
    float* __restrict__ rsp)
{
    __shared__ float shA[16][68];
    __shared__ float shT[16][68];
    const int b  = blockIdx.z;
    const int nq = blockIdx.y;
    const int m0 = blockIdx.x * 64;
    const u16* Pb = phi   + (size_t)b * C_ * N_;
    const u16* Tb = theta + (size_t)b * C_ * N_;
    const int t  = threadIdx.x;
    const int tm = t >> 4, tn = t & 15;
    const int sr = t >> 4;
    const int sc = (t & 15) * 4;

    float rs[4] = {0.f, 0.f, 0.f, 0.f};

    for (int nt = 0; nt < 8; ++nt) {
        const int n0 = nq * 512 + nt * 64;
        float acc[4][4] = {};
        for (int kb = 0; kb < 256; kb += 16) {
            __syncthreads();
            const ushort4 va = *(const ushort4*)&Pb[(size_t)(kb + sr) * N_ + m0 + sc];
            const ushort4 vt = *(const ushort4*)&Tb[(size_t)(kb + sr) * N_ + n0 + sc];
            shA[sr][sc+0] = bf2f(va.x); shA[sr][sc+1] = bf2f(va.y);
            shA[sr][sc+2] = bf2f(va.z); shA[sr][sc+3] = bf2f(va.w);
            shT[sr][sc+0] = bf2f(vt.x); shT[sr][sc+1] = bf2f(vt.y);
            shT[sr][sc+2] = bf2f(vt.z); shT[sr][sc+3] = bf2f(vt.w);
            __syncthreads();
            #pragma unroll
            for (int kk = 0; kk < 16; ++kk) {
                const float4 av = *(const float4*)&shA[kk][tm * 4];
                const float4 bv = *(const float4*)&shT[kk][tn * 4];
                const float a0[4] = {av.x, av.y, av.z, av.w};
                const float b0[4] = {bv.x, bv.y, bv.z, bv.w};
                #pragma unroll
                for (int i = 0; i < 4; ++i)
                    #pragma unroll
                    for (int j = 0; j < 4; ++j)
                        acc[i][j] = fmaf(a0[i], b0[j], acc[i][j]);
            }
        }
        #pragma unroll
        for (int i = 0; i < 4; ++i)
            #pragma unroll
            for (int j = 0; j < 4; ++j)
                rs[i] += __expf(acc[i][j]);
    }
    #pragma unroll
    for (int i = 0; i < 4; ++i) {
        float v = rs[i];
        v += __shfl_xor(v, 1);
        v += __shfl_xor(v, 2);
        v += __shfl_xor(v, 4);
        v += __shfl_xor(v, 8);
        if (tn == 0)
            rsp[((size_t)nq * B_ + b) * N_ + m0 + tm * 4 + i] = v;
    }
}

// ---------------------------------------------------------------------------
// Pass B: fused S-recompute + softmax-normalize + PV contraction.
// Block: n-tile of 32 cols, m-half (1024), batch.  Output: ytp[half][b][256][2048] bf16.
// ---------------------------------------------------------------------------
__global__ __launch_bounds__(256) void passB_pv(
    const u16* __restrict__ phi, const u16* __restrict__ theta,
    const u16* __restrict__ g, const float* __restrict__ rsp,
    u16* __restrict__ ytp)
{
    __shared__ float shPhi[16][68];
    __shared__ float shTh[16][36];
    __shared__ float shP[64][36];
    __shared__ float shG[16][264];
    __shared__ float shInv[64];

    const int b    = blockIdx.z;
    const int half = blockIdx.y;
    const int n0   = blockIdx.x * 32;
    const int t    = threadIdx.x;
    const size_t bstr = (size_t)C_ * N_;
    const u16* Pb = phi   + (size_t)b * bstr;
    const u16* Tb = theta + (size_t)b * bstr;
    const u16* Gb = g     + (size_t)b * bstr;

    const int tc = t >> 3;          // 0..31 -> c rows tc*8..+7
    const int nS = (t & 7) * 4;     // n cols nS..+3
    const int mS = (t >> 3) * 2;    // Stile rows mS, mS+1

    float acc[8][4] = {};

    for (int mt = 0; mt < 16; ++mt) {
        const int mbase = half * 1024 + mt * 64;
        __syncthreads();
        if (t < 64) {
            const int m = mbase + t;
            const float s = rsp[(0 * B_ + b) * (size_t)N_ + m]
                          + rsp[(1 * B_ + b) * (size_t)N_ + m]
                          + rsp[(2 * B_ + b) * (size_t)N_ + m]
                          + rsp[(3 * B_ + b) * (size_t)N_ + m];
            shInv[t] = 1.0f / s;
        }
        float accs[2][4] = {};
        for (int kb = 0; kb < 256; kb += 16) {
            __syncthreads();
            {
                const ushort4 v = *(const ushort4*)&Pb[(size_t)(kb + (t >> 4)) * N_ + mbase + (t & 15) * 4];
                const int r = t >> 4, c4 = (t & 15) * 4;
                shPhi[r][c4+0] = bf2f(v.x); shPhi[r][c4+1] = bf2f(v.y);
                shPhi[r][c4+2] = bf2f(v.z); shPhi[r][c4+3] = bf2f(v.w);
            }
            if (t < 128) {
                const ushort4 v = *(const ushort4*)&Tb[(size_t)(kb + (t >> 3)) * N_ + n0 + (t & 7) * 4];
                const int r = t >> 3, c4 = (t & 7) * 4;
                shTh[r][c4+0] = bf2f(v.x); shTh[r][c4+1] = bf2f(v.y);
                shTh[r][c4+2] = bf2f(v.z); shTh[r][c4+3] = bf2f(v.w);
            }
            __syncthreads();
            #pragma unroll
            for (int kk = 0; kk < 16; ++kk) {
                const float2 av = *(const float2*)&shPhi[kk][mS];
                const float4 bv = *(const float4*)&shTh[kk][nS];
                const float a0[2] = {av.x, av.y};
                const float b0[4] = {bv.x, bv.y, bv.z, bv.w};
                #pragma unroll
                for (int i = 0; i < 2; ++i)
                    #pragma unroll
                    for (int j = 0; j < 4; ++j)
                        accs[i][j] = fmaf(a0[i], b0[j], accs[i][j]);
            }
        }
        __syncthreads();
        {
            const float i0 = shInv[mS], i1 = shInv[mS + 1];
            float4 p0, p1;
            p0.x = __expf(accs[0][0]) * i0; p0.y = __expf(accs[0][1]) * i0;
            p0.z = __expf(accs[0][2]) * i0; p0.w = __expf(accs[0][3]) * i0;
            p1.x = __expf(accs[1][0]) * i1; p1.y = __expf(accs[1][1]) * i1;
            p1.z = __expf(accs[1][2]) * i1; p1.w = __expf(accs[1][3]) * i1;
            *(float4*)&shP[mS][nS]     = p0;
            *(float4*)&shP[mS + 1][nS] = p1;
        }
        #pragma unroll
        for (int mc = 0; mc < 4; ++mc) {
            __syncthreads();
            {
                const u16* gr = &Gb[(size_t)t * N_ + mbase + mc * 16];
                #pragma unroll
                for (int q = 0; q < 4; ++q) {
                    const ushort4 v = *(const ushort4*)&gr[q * 4];
                    shG[q * 4 + 0][t] = bf2f(v.x);
                    shG[q * 4 + 1][t] = bf2f(v.y);
                    shG[q * 4 + 2][t] = bf2f(v.z);
                    shG[q * 4 + 3][t] = bf2f(v.w);
                }
            }
            __syncthreads();
            #pragma unroll
            for (int mm = 0; mm < 16; ++mm) {
                const float4 pv = *(const float4*)&shP[mc * 16 + mm][nS];
                const float4 g0 = *(const float4*)&shG[mm][tc * 8];
                const float4 g1 = *(const float4*)&shG[mm][tc * 8 + 4];
                const float pj[4] = {pv.x, pv.y, pv.z, pv.w};
                const float ga[8] = {g0.x, g0.y, g0.z, g0.w, g1.x, g1.y, g1.z, g1.w};
                #pragma unroll
                for (int i = 0; i < 8; ++i)
                    #pragma unroll
                    for (int j = 0; j < 4; ++j)
                        acc[i][j] = fmaf(ga[i], pj[j], acc[i][j]);
            }
        }
    }
    u16* Yb = ytp + ((size_t)half * B_ + b) * bstr;
    #pragma unroll
    for (int i = 0; i < 8; ++i) {
        ushort4 o;
        o.x = f2bf(acc[i][0]); o.y = f2bf(acc[i][1]);
        o.z = f2bf(acc[i][2]); o.w = f2bf(acc[i][3]);
        *(ushort4*)&Yb[(size_t)(tc * 8 + i) * N_ + n0 + nS] = o;
    }
}

// ---------------------------------------------------------------------------
// Kernel 4: out[b][o][p] += sum_k W_mask[o][k] * (Yt0 + Yt1)(128x4096)[k][p]
// ---------------------------------------------------------------------------
__global__ __launch_bounds__(256) void mask_add_kernel(
    const u16* __restrict__ ytp, const float* __restrict__ Wm,
    float* __restrict__ out)
{
    const int p  = blockIdx.x * 256 + threadIdx.x;
    const int og = blockIdx.y;   // 0..31 -> o = og*8 .. +7
    const int b  = blockIdx.z;
    const size_t bstr = (size_t)C_ * N_;   // == 128*4096
    const u16* Y0 = ytp + (size_t)b * bstr;
    const u16* Y1 = ytp + ((size_t)B_ + b) * bstr;

    float acc[8] = {};
    for (int k = 0; k < 128; ++k) {
        const float y = bf2f(Y0[(size_t)k * HW + p]) + bf2f(Y1[(size_t)k * HW + p]);
        #pragma unroll
        for (int j = 0; j < 8; ++j)
            acc[j] = fmaf(Wm[(og * 8 + j) * 128 + k], y, acc[j]);
    }
    float* ob = out + (size_t)b * C_ * HW;
    #pragma unroll
    for (int j = 0; j < 8; ++j)
        ob[(size_t)(og * 8 + j) * HW + p] += acc[j];
}

// ---------------------------------------------------------------------------
extern "C" void kernel_launch(void* const* d_in, const int* in_sizes, int n_in,
                              void* d_out, int out_size, void* d_ws, size_t ws_size,
                              hipStream_t stream)
{
    const float* A      = (const float*)d_in[0];
    const float* Bx     = (const float*)d_in[1];
    const float* Wphi   = (const float*)d_in[2];
    const float* Wtheta = (const float*)d_in[3];
    const float* Wg     = (const float*)d_in[4];
    const float* Wab    = (const float*)d_in[5];
    const float* Wmask  = (const float*)d_in[6];
    float* out = (float*)d_out;

    // workspace layout (~20.1 MB total)
    u16*   phi   = (u16*)d_ws;                 // 4*128*4096 = 2M bf16 = 4 MB
    u16*   theta = phi + 2097152;              // 4 MB
    u16*   g     = theta + 2097152;            // 4 MB
    float* rsp   = (float*)(g + 2097152);      // 4*4*2048 f32 = 128 KB
    u16*   ytp   = (u16*)(rsp + 32768);        // 2*4*256*2048 bf16 = 8 MB

    convs_kernel<<<dim3(16, 16, 4), 256, 0, stream>>>(
        A, Bx, Wphi, Wtheta, Wg, Wab, phi, theta, g, out);

    passA_rowsum<<<dim3(32, 4, 4), 256, 0, stream>>>(phi, theta, rsp);

    passB_pv<<<dim3(64, 2, 4), 256, 0, stream>>>(phi, theta, g, rsp, ytp);

    mask_add_kernel<<<dim3(16, 32, 4), 256, 0, stream>>>(ytp, Wmask, out);
}

// Round 4
// 718.891 us; speedup vs baseline: 1.8251x; 1.8251x over previous
//
#include <hip/hip_runtime.h>
#include <hip/hip_bf16.h>

#define B_    4
#define C_    256
#define HW    4096
#define N_    2048   // seq len after the (b,256,2048) reinterpretation
#define BSTR  524288 // 256*2048 elements per batch for phit/thetat/g/Yt

typedef unsigned short u16;
using f32x4 = __attribute__((ext_vector_type(4))) float;
using u32x4 = __attribute__((ext_vector_type(4))) unsigned int;

__device__ __forceinline__ float bf2f(u16 u) {
    return __uint_as_float(((unsigned)u) << 16);
}
__device__ __forceinline__ u16 f2bf(float f) {
    unsigned x = __float_as_uint(f);
    x += 0x7fff + ((x >> 16) & 1);   // RNE
    return (u16)(x >> 16);
}

// MFMA via inline asm. Hazards handled manually: chained same-acc MFMAs need
// no waits; VALU reads of acc go through mfma_fence; VALU-written operands
// get an s_nop-prefixed variant.
__device__ __forceinline__ void mfma_bf16(f32x4& acc, u32x4 a, u32x4 b) {
    asm volatile("v_mfma_f32_16x16x32_bf16 %0, %1, %2, %0"
                 : "+v"(acc) : "v"(a), "v"(b));
}
__device__ __forceinline__ void mfma_bf16_vsrc(f32x4& acc, u32x4 a, u32x4 b) {
    asm volatile("s_nop 1\n\tv_mfma_f32_16x16x32_bf16 %0, %1, %2, %0"
                 : "+v"(acc) : "v"(a), "v"(b));
}
__device__ __forceinline__ void mfma_fence(f32x4& x) {
    asm volatile("s_nop 7\n\ts_nop 7" : "+v"(x));
}

// ---------------------------------------------------------------------------
// Kernel 1: fused 1x1 convs + W_AB residual.
//   outputs: phit [m][c'] bf16 (k-fastest, via LDS transpose)
//            thetat [n][c'] bf16
//            g     [c''][m] bf16 (flat-identical to [c][p] conv output)
//            out   [o][p]  f32 residual
// ---------------------------------------------------------------------------
__global__ __launch_bounds__(256) void convs_kernel(
    const float* __restrict__ A, const float* __restrict__ Bx,
    const float* __restrict__ Wphi, const float* __restrict__ Wtheta,
    const float* __restrict__ Wg, const float* __restrict__ Wab,
    u16* __restrict__ phit, u16* __restrict__ thetat,
    u16* __restrict__ g, float* __restrict__ out)
{
    const int t  = threadIdx.x;
    const int h  = t >> 7;                    // parity (p high/low half)
    const int r  = t & 127;
    const int pl = blockIdx.x * 128 + r;      // m index 0..2047
    const int p  = pl + h * 2048;
    const int og = blockIdx.y;                // 0..15
    const int b  = blockIdx.z;
    const float* Ab = A  + (size_t)b * C_ * HW;
    const float* Bb = Bx + (size_t)b * C_ * HW;

    float accP[8] = {}, accT[8] = {}, accG[8] = {}, accO[16] = {};

    for (int c = 0; c < C_; ++c) {
        const float a  = Ab[c * HW + p];
        const float bb = Bb[c * HW + p];
        #pragma unroll
        for (int j = 0; j < 8; ++j) {
            const int o = og * 8 + j;
            accP[j] = fmaf(Wphi[o * C_ + c],          a,  accP[j]);
            accT[j] = fmaf(Wtheta[o * C_ + c],        bb, accT[j]);
            accG[j] = fmaf(Wg[o * 2 * C_ + c],        a,  accG[j]);
            accG[j] = fmaf(Wg[o * 2 * C_ + C_ + c],   bb, accG[j]);
        }
        #pragma unroll
        for (int j = 0; j < 16; ++j) {
            const int o2 = og * 16 + j;
            accO[j] = fmaf(Wab[o2 * 2 * C_ + c],      a,  accO[j]);
            accO[j] = fmaf(Wab[o2 * 2 * C_ + C_ + c], bb, accO[j]);
        }
    }

    u16* gb = g + b * BSTR;
    #pragma unroll
    for (int j = 0; j < 8; ++j)
        gb[(og * 8 + j) * HW + p] = f2bf(accG[j]);
    float* ob = out + (size_t)b * C_ * HW;
    #pragma unroll
    for (int j = 0; j < 16; ++j)
        ob[(og * 16 + j) * HW + p] = accO[j];

    // phit/thetat via LDS transpose: tile rows m (=pl), cols c' = 2c + h
    __shared__ u16 tP[128][24];
    __shared__ u16 tT[128][24];
    #pragma unroll
    for (int j = 0; j < 8; ++j) {
        tP[r][2 * j + h] = f2bf(accP[j]);
        tT[r][2 * j + h] = f2bf(accT[j]);
    }
    __syncthreads();
    {
        const int row = t >> 1, half = t & 1;
        const uint4 vp = *(const uint4*)&tP[row][half * 8];
        const uint4 vt = *(const uint4*)&tT[row][half * 8];
        const int off = b * BSTR + (blockIdx.x * 128 + row) * 256 + og * 16 + half * 8;
        *(uint4*)&phit[off]   = vp;
        *(uint4*)&thetat[off] = vt;
    }
}

// ---------------------------------------------------------------------------
// Pass A (MFMA): partial row-sums of exp(S), S[m][n] = sum_c phit[m][c]*thetat[n][c].
// ---------------------------------------------------------------------------
__global__ __launch_bounds__(256) void passA_mfma(
    const u16* __restrict__ phit, const u16* __restrict__ thetat,
    float* __restrict__ rs)
{
    __shared__ __align__(16) u16 shP[64 * 256];
    __shared__ __align__(16) u16 shT[64 * 256];
    const int t = threadIdx.x, b = blockIdx.z, nq = blockIdx.y, mb = blockIdx.x;
    const u16* Pb = phit   + b * BSTR + mb * 64 * 256;
    const u16* Tb = thetat + b * BSTR + nq * 512 * 256;

    #pragma unroll
    for (int i = 0; i < 8; ++i) {              // stage phit tile [64][256]
        const int q = i * 256 + t;
        const int row = q >> 5, c16 = (q & 31) * 8;
        const uint4 v = *(const uint4*)&Pb[row * 256 + c16];
        *(uint4*)&shP[row * 256 + (c16 ^ ((row & 7) << 3))] = v;
    }
    __syncthreads();

    const int lane = t & 63, w = t >> 6, lo = lane & 15, hi = lane >> 4;
    u32x4 afr[8];
    {
        const int row = w * 16 + lo;
        #pragma unroll
        for (int kb = 0; kb < 8; ++kb)
            afr[kb] = *(const u32x4*)&shP[row * 256 + ((kb * 32 + hi * 8) ^ ((row & 7) << 3))];
    }

    float rsacc[4] = {0.f, 0.f, 0.f, 0.f};
    for (int nt = 0; nt < 8; ++nt) {
        __syncthreads();
        #pragma unroll
        for (int i = 0; i < 8; ++i) {          // stage thetat tile [64][256]
            const int q = i * 256 + t;
            const int row = q >> 5, c16 = (q & 31) * 8;
            const uint4 v = *(const uint4*)&Tb[(nt * 64 + row) * 256 + c16];
            *(uint4*)&shT[row * 256 + (c16 ^ ((row & 7) << 3))] = v;
        }
        __syncthreads();
        #pragma unroll
        for (int ns = 0; ns < 4; ++ns) {
            f32x4 acc = {0.f, 0.f, 0.f, 0.f};
            const int row = ns * 16 + lo;
            #pragma unroll
            for (int kb = 0; kb < 8; ++kb) {
                const u32x4 bfr = *(const u32x4*)&shT[row * 256 + ((kb * 32 + hi * 8) ^ ((row & 7) << 3))];
                mfma_bf16(acc, afr[kb], bfr);
            }
            mfma_fence(acc);
            rsacc[0] += __expf(acc.x); rsacc[1] += __expf(acc.y);
            rsacc[2] += __expf(acc.z); rsacc[3] += __expf(acc.w);
        }
    }
    #pragma unroll
    for (int q = 0; q < 4; ++q) {
        float v = rsacc[q];
        v += __shfl_xor(v, 1); v += __shfl_xor(v, 2);
        v += __shfl_xor(v, 4); v += __shfl_xor(v, 8);
        rsacc[q] = v;
    }
    if (lo == 0) {
        const int m = mb * 64 + w * 16 + hi * 4;
        float* dst = rs + (nq * 4 + b) * N_ + m;
        dst[0] = rsacc[0]; dst[1] = rsacc[1]; dst[2] = rsacc[2]; dst[3] = rsacc[3];
    }
}

// ---------------------------------------------------------------------------
// Pass B (MFMA, flash-style): recompute S tile-by-tile, P = exp(S)*inv[m] in
// registers (bf16-packed), PV-accumulate Yt[c''][n] = sum_m g[c''][m] P[m][n].
// ---------------------------------------------------------------------------
__global__ __launch_bounds__(256) void passB_mfma(
    const u16* __restrict__ phit, const u16* __restrict__ thetat,
    const u16* __restrict__ g, const float* __restrict__ rs,
    u16* __restrict__ Yt)
{
    __shared__ __align__(16) u16 shT[64 * 256];   // theta n-tile (block-constant)
    __shared__ __align__(16) u16 shPm[32 * 256];  // phit m-step tile
    __shared__ __align__(16) u16 shG[64 * 32];    // g c''-tile for m-step
    __shared__ float shInv[32];

    const int t = threadIdx.x, b = blockIdx.z, ch = blockIdx.y, nb = blockIdx.x;
    const u16* Tb = thetat + b * BSTR + nb * 64 * 256;
    const u16* Pb = phit + b * BSTR;
    const u16* Gb = g + b * BSTR + ch * 64 * N_;
    const int lane = t & 63, w = t >> 6, lo = lane & 15, hi = lane >> 4;

    #pragma unroll
    for (int i = 0; i < 8; ++i) {                 // stage theta once
        const int q = i * 256 + t;
        const int row = q >> 5, c16 = (q & 31) * 8;
        const uint4 v = *(const uint4*)&Tb[row * 256 + c16];
        *(uint4*)&shT[row * 256 + (c16 ^ ((row & 7) << 3))] = v;
    }
    __syncthreads();
    u32x4 bfr[8];                                 // wave's theta B-frags (held)
    {
        const int row = w * 16 + lo;
        #pragma unroll
        for (int kb = 0; kb < 8; ++kb)
            bfr[kb] = *(const u32x4*)&shT[row * 256 + ((kb * 32 + hi * 8) ^ ((row & 7) << 3))];
    }

    f32x4 accY[4];
    #pragma unroll
    for (int ct = 0; ct < 4; ++ct) accY[ct] = (f32x4){0.f, 0.f, 0.f, 0.f};

    for (int mt = 0; mt < 64; ++mt) {
        __syncthreads();
        #pragma unroll
        for (int i = 0; i < 4; ++i) {             // stage phit [32 m][256]
            const int q = i * 256 + t;
            const int row = q >> 5, c16 = (q & 31) * 8;
            const uint4 v = *(const uint4*)&Pb[(mt * 32 + row) * 256 + c16];
            *(uint4*)&shPm[row * 256 + (c16 ^ ((row & 7) << 3))] = v;
        }
        {                                         // stage g [64 c''][32 m] (FULL tile)
            const int row = t >> 2, qd = t & 3;   // 64 rows x 4 quads of 8 m
            const uint4 v = *(const uint4*)&Gb[row * N_ + mt * 32 + qd * 8];
            const int base = row * 32, m0 = qd * 8, sw = (row & 7) << 2;
            *(uint2*)&shG[base + ((m0    ) ^ sw)] = make_uint2(v.x, v.y);
            *(uint2*)&shG[base + ((m0 + 4) ^ sw)] = make_uint2(v.z, v.w);
        }
        if (t < 32) {                             // inv row-sums for this m-step
            const float* rp = rs + b * N_ + mt * 32 + t;
            shInv[t] = 1.0f / (rp[0] + rp[8192] + rp[16384] + rp[24576]);
        }
        __syncthreads();

        // S tiles: this wave's 16 n-cols, m-subtiles 0/1 (rows mt*32 + 0..31)
        f32x4 s0 = {0.f, 0.f, 0.f, 0.f}, s1 = {0.f, 0.f, 0.f, 0.f};
        {
            const int row = lo;
            #pragma unroll
            for (int kb = 0; kb < 8; ++kb) {
                const u32x4 a = *(const u32x4*)&shPm[row * 256 + ((kb * 32 + hi * 8) ^ ((row & 7) << 3))];
                mfma_bf16(s0, a, bfr[kb]);
            }
        }
        {
            const int row = 16 + lo;
            #pragma unroll
            for (int kb = 0; kb < 8; ++kb) {
                const u32x4 a = *(const u32x4*)&shPm[row * 256 + ((kb * 32 + hi * 8) ^ ((row & 7) << 3))];
                mfma_bf16(s1, a, bfr[kb]);
            }
        }
        mfma_fence(s0); mfma_fence(s1);

        // P = exp(S) * inv[m]; pack bf16 with kmap(hi,e)=(e>>2)*16+hi*4+(e&3)
        float p0[4], p1[4];
        #pragma unroll
        for (int q = 0; q < 4; ++q) {
            p0[q] = __expf(s0[q]) * shInv[hi * 4 + q];
            p1[q] = __expf(s1[q]) * shInv[16 + hi * 4 + q];
        }
        u32x4 pf;
        pf[0] = (unsigned)f2bf(p0[0]) | ((unsigned)f2bf(p0[1]) << 16);
        pf[1] = (unsigned)f2bf(p0[2]) | ((unsigned)f2bf(p0[3]) << 16);
        pf[2] = (unsigned)f2bf(p1[0]) | ((unsigned)f2bf(p1[1]) << 16);
        pf[3] = (unsigned)f2bf(p1[2]) | ((unsigned)f2bf(p1[3]) << 16);

        // PV: accY[ct] += G-frag(ct) * P   (G A-frag uses the same kmap)
        #pragma unroll
        for (int ct = 0; ct < 4; ++ct) {
            const int row = ct * 16 + lo;
            const int sw = (row & 7) << 2, m4 = hi * 4;
            const uint2 a0 = *(const uint2*)&shG[row * 32 + ((m4     ) ^ sw)];
            const uint2 a1 = *(const uint2*)&shG[row * 32 + ((16 + m4) ^ sw)];
            u32x4 gf; gf[0] = a0.x; gf[1] = a0.y; gf[2] = a1.x; gf[3] = a1.y;
            mfma_bf16_vsrc(accY[ct], gf, pf);
        }
    }

    // epilogue: Yt[c''][n] bf16
    u16* Yb = Yt + b * BSTR;
    #pragma unroll
    for (int ct = 0; ct < 4; ++ct) {
        mfma_fence(accY[ct]);
        const int crow = ch * 64 + ct * 16 + hi * 4;
        const int col  = nb * 64 + w * 16 + lo;
        #pragma unroll
        for (int q = 0; q < 4; ++q)
            Yb[(crow + q) * N_ + col] = f2bf(accY[ct][q]);
    }
}

// ---------------------------------------------------------------------------
// Kernel 4: out[o][p] += sum_k W_mask[o][k] * Yview[k][p]
// ---------------------------------------------------------------------------
__global__ __launch_bounds__(256) void mask_add_kernel(
    const u16* __restrict__ Yt, const float* __restrict__ Wm,
    float* __restrict__ out)
{
    const int p  = blockIdx.x * 256 + threadIdx.x;
    const int og = blockIdx.y;
    const int b  = blockIdx.z;
    const u16* Yb = Yt + b * BSTR;

    float acc[8] = {};
    for (int k = 0; k < 128; ++k) {
        const float y = bf2f(Yb[k * HW + p]);
        #pragma unroll
        for (int j = 0; j < 8; ++j)
            acc[j] = fmaf(Wm[(og * 8 + j) * 128 + k], y, acc[j]);
    }
    float* ob = out + (size_t)b * C_ * HW;
    #pragma unroll
    for (int j = 0; j < 8; ++j)
        ob[(og * 8 + j) * HW + p] += acc[j];
}

// ---------------------------------------------------------------------------
extern "C" void kernel_launch(void* const* d_in, const int* in_sizes, int n_in,
                              void* d_out, int out_size, void* d_ws, size_t ws_size,
                              hipStream_t stream)
{
    const float* A      = (const float*)d_in[0];
    const float* Bx     = (const float*)d_in[1];
    const float* Wphi   = (const float*)d_in[2];
    const float* Wtheta = (const float*)d_in[3];
    const float* Wg     = (const float*)d_in[4];
    const float* Wab    = (const float*)d_in[5];
    const float* Wmask  = (const float*)d_in[6];
    float* out = (float*)d_out;

    // workspace (~16.9 MB)
    u16*   phit   = (u16*)d_ws;                // [4][2048][256] bf16
    u16*   thetat = phit + 4 * BSTR;           // [4][2048][256]
    u16*   g      = thetat + 4 * BSTR;         // [4][256][2048]
    float* rs     = (float*)(g + 4 * BSTR);    // [4 nq][4 b][2048] f32
    u16*   Yt     = (u16*)(rs + 32768);        // [4][256][2048] bf16

    convs_kernel<<<dim3(16, 16, 4), 256, 0, stream>>>(
        A, Bx, Wphi, Wtheta, Wg, Wab, phit, thetat, g, out);

    passA_mfma<<<dim3(32, 4, 4), 256, 0, stream>>>(phit, thetat, rs);

    passB_mfma<<<dim3(32, 4, 4), 256, 0, stream>>>(phit, thetat, g, rs, Yt);

    mask_add_kernel<<<dim3(16, 32, 4), 256, 0, stream>>>(Yt, Wmask, out);
}

// Round 5
// 276.095 us; speedup vs baseline: 4.7522x; 2.6038x over previous
//
#include <hip/hip_runtime.h>
#include <hip/hip_bf16.h>

#define B_    4
#define C_    256
#define HW    4096
#define N_    2048   // seq len after the (b,256,2048) reinterpretation
#define BSTR  524288 // 256*2048 elements per batch for phit/thetat/g/Yt

typedef unsigned short u16;
using f32x4 = __attribute__((ext_vector_type(4))) float;
using u32x4 = __attribute__((ext_vector_type(4))) unsigned int;

__device__ __forceinline__ float bf2f(u16 u) {
    return __uint_as_float(((unsigned)u) << 16);
}
__device__ __forceinline__ u16 f2bf(float f) {
    unsigned x = __float_as_uint(f);
    x += 0x7fff + ((x >> 16) & 1);   // RNE
    return (u16)(x >> 16);
}

// MFMA via inline asm. Hazards handled manually: chained same-acc MFMAs need
// no waits; VALU reads of acc go through mfma_fence; VALU-written operands
// get an s_nop-prefixed variant.
__device__ __forceinline__ void mfma_bf16(f32x4& acc, u32x4 a, u32x4 b) {
    asm volatile("v_mfma_f32_16x16x32_bf16 %0, %1, %2, %0"
                 : "+v"(acc) : "v"(a), "v"(b));
}
__device__ __forceinline__ void mfma_bf16_vsrc(f32x4& acc, u32x4 a, u32x4 b) {
    asm volatile("s_nop 1\n\tv_mfma_f32_16x16x32_bf16 %0, %1, %2, %0"
                 : "+v"(acc) : "v"(a), "v"(b));
}
__device__ __forceinline__ void mfma_fence(f32x4& x) {
    asm volatile("s_nop 7\n\ts_nop 7" : "+v"(x));
}

// ---------------------------------------------------------------------------
// prep_w: pack weights into Wt [640][512] bf16, k-fastest.
//   rows   0..127 : [Wphi | 0]        (phi: A channels only)
//   rows 128..255 : [0 | Wtheta]      (theta: B channels only)
//   rows 256..383 : Wg  (full 512)
//   rows 384..639 : Wab (full 512)
// ---------------------------------------------------------------------------
__global__ __launch_bounds__(256) void prep_w(
    const float* __restrict__ Wphi, const float* __restrict__ Wtheta,
    const float* __restrict__ Wg, const float* __restrict__ Wab,
    u16* __restrict__ Wt)
{
    const int row = blockIdx.x;          // 0..639
    const int t   = threadIdx.x;
    #pragma unroll
    for (int i = 0; i < 2; ++i) {
        const int col = i * 256 + t;
        float v;
        if (row < 128)      v = (col < 256)  ? Wphi[row * 256 + col] : 0.f;
        else if (row < 256) v = (col >= 256) ? Wtheta[(row - 128) * 256 + (col - 256)] : 0.f;
        else if (row < 384) v = Wg[(row - 256) * 512 + col];
        else                v = Wab[(row - 384) * 512 + col];
        Wt[row * 512 + col] = f2bf(v);
    }
}

// ---------------------------------------------------------------------------
// prep_abt: cast+transpose A,B (f32 [b][256][4096]) -> ABt bf16 [b][4096][512]
// (k-fastest: cols 0..255 = A channels, 256..511 = B channels).
// ---------------------------------------------------------------------------
__global__ __launch_bounds__(256) void prep_abt(
    const float* __restrict__ A, const float* __restrict__ Bx,
    u16* __restrict__ ABt)
{
    __shared__ u16 L[64][528];           // 528 pad: 16B-aligned rows
    const int t = threadIdx.x, pb = blockIdx.x, b = blockIdx.y;
    const int p0 = pb * 64;
    const int pl = t & 63, cg = t >> 6;
    const float* Ab = A  + (size_t)b * C_ * HW;
    const float* Bb = Bx + (size_t)b * C_ * HW;

    for (int i = 0; i < 64; ++i) {
        const int c = cg + i * 4;
        L[pl][c]       = f2bf(Ab[c * HW + p0 + pl]);
        L[pl][256 + c] = f2bf(Bb[c * HW + p0 + pl]);
    }
    __syncthreads();
    u16* dst = ABt + ((size_t)b * 4096 + p0) * 512;
    #pragma unroll
    for (int i = 0; i < 16; ++i) {
        const int idx = i * 256 + t;
        const int row = idx >> 6, ch = idx & 63;
        *(uint4*)&dst[row * 512 + ch * 8] = *(const uint4*)&L[row][ch * 8];
    }
}

// ---------------------------------------------------------------------------
// conv_gemm: C[o][p] = sum_k Wt[o][k] * ABt[p][k]  (per batch), o in [0,640).
// Block: 64 o (chunk nb) x 64 p (tile pb), K=512 in 4 steps of 128.
// Epilogue routes each chunk to its layout:
//   nb 0-1: phit[m][h*128+o]  (h-major k-permutation, shared with thetat)
//   nb 2-3: thetat[m][h*128+(o-128)]
//   nb 4-5: g[o-256][p]   (row-major = the [c''][m] view)
//   nb 6-9: out[o-384][p] f32 residual
// ---------------------------------------------------------------------------
__global__ __launch_bounds__(256) void conv_gemm(
    const u16* __restrict__ Wt, const u16* __restrict__ ABt,
    u16* __restrict__ phit, u16* __restrict__ thetat,
    u16* __restrict__ g, float* __restrict__ out)
{
    __shared__ __align__(16) u16 shW[64 * 128];
    __shared__ __align__(16) u16 shAB[64 * 128];
    const int t = threadIdx.x, pb = blockIdx.x, nb = blockIdx.y, b = blockIdx.z;
    const int lane = t & 63, w = t >> 6, lo = lane & 15, hi = lane >> 4;
    const u16* Wb = Wt + nb * 64 * 512;
    const u16* Ab = ABt + ((size_t)b * 4096 + pb * 64) * 512;

    f32x4 acc[4];
    #pragma unroll
    for (int ot = 0; ot < 4; ++ot) acc[ot] = (f32x4){0.f, 0.f, 0.f, 0.f};

    for (int ks = 0; ks < 4; ++ks) {
        __syncthreads();
        #pragma unroll
        for (int i = 0; i < 4; ++i) {
            const int q = i * 256 + t;
            const int row = q >> 4, c16 = (q & 15) * 8;
            const int sw = (row & 7) << 3;
            *(uint4*)&shW[row * 128 + (c16 ^ sw)]  = *(const uint4*)&Wb[row * 512 + ks * 128 + c16];
            *(uint4*)&shAB[row * 128 + (c16 ^ sw)] = *(const uint4*)&Ab[row * 512 + ks * 128 + c16];
        }
        __syncthreads();
        u32x4 bfr[4];
        {
            const int row = w * 16 + lo, sw = (row & 7) << 3;
            #pragma unroll
            for (int kf = 0; kf < 4; ++kf)
                bfr[kf] = *(const u32x4*)&shAB[row * 128 + ((kf * 32 + hi * 8) ^ sw)];
        }
        #pragma unroll
        for (int ot = 0; ot < 4; ++ot) {
            const int row = ot * 16 + lo, sw = (row & 7) << 3;
            #pragma unroll
            for (int kf = 0; kf < 4; ++kf) {
                const u32x4 a = *(const u32x4*)&shW[row * 128 + ((kf * 32 + hi * 8) ^ sw)];
                mfma_bf16(acc[ot], a, bfr[kf]);
            }
        }
    }

    const int p_global = pb * 64 + w * 16 + lo;
    const int m = p_global & 2047, h = p_global >> 11;
    #pragma unroll
    for (int ot = 0; ot < 4; ++ot) {
        mfma_fence(acc[ot]);
        const int ob = nb * 64 + ot * 16 + hi * 4;
        if (nb < 2) {
            ushort4 v;
            v.x = f2bf(acc[ot][0]); v.y = f2bf(acc[ot][1]);
            v.z = f2bf(acc[ot][2]); v.w = f2bf(acc[ot][3]);
            *(ushort4*)&phit[(size_t)b * BSTR + m * 256 + h * 128 + ob] = v;
        } else if (nb < 4) {
            ushort4 v;
            v.x = f2bf(acc[ot][0]); v.y = f2bf(acc[ot][1]);
            v.z = f2bf(acc[ot][2]); v.w = f2bf(acc[ot][3]);
            *(ushort4*)&thetat[(size_t)b * BSTR + m * 256 + h * 128 + (ob - 128)] = v;
        } else if (nb < 6) {
            #pragma unroll
            for (int q = 0; q < 4; ++q)
                g[(size_t)b * BSTR + (ob - 256 + q) * HW + p_global] = f2bf(acc[ot][q]);
        } else {
            #pragma unroll
            for (int q = 0; q < 4; ++q)
                out[(size_t)b * C_ * HW + (size_t)(ob - 384 + q) * HW + p_global] = acc[ot][q];
        }
    }
}

// ---------------------------------------------------------------------------
// Pass A (MFMA): partial row-sums of exp(S), S[m][n] = sum_c phit[m][c]*thetat[n][c].
// ---------------------------------------------------------------------------
__global__ __launch_bounds__(256) void passA_mfma(
    const u16* __restrict__ phit, const u16* __restrict__ thetat,
    float* __restrict__ rs)
{
    __shared__ __align__(16) u16 shP[64 * 256];
    __shared__ __align__(16) u16 shT[64 * 256];
    const int t = threadIdx.x, b = blockIdx.z, nq = blockIdx.y, mb = blockIdx.x;
    const u16* Pb = phit   + b * BSTR + mb * 64 * 256;
    const u16* Tb = thetat + b * BSTR + nq * 512 * 256;

    #pragma unroll
    for (int i = 0; i < 8; ++i) {
        const int q = i * 256 + t;
        const int row = q >> 5, c16 = (q & 31) * 8;
        const uint4 v = *(const uint4*)&Pb[row * 256 + c16];
        *(uint4*)&shP[row * 256 + (c16 ^ ((row & 7) << 3))] = v;
    }
    __syncthreads();

    const int lane = t & 63, w = t >> 6, lo = lane & 15, hi = lane >> 4;
    u32x4 afr[8];
    {
        const int row = w * 16 + lo;
        #pragma unroll
        for (int kb = 0; kb < 8; ++kb)
            afr[kb] = *(const u32x4*)&shP[row * 256 + ((kb * 32 + hi * 8) ^ ((row & 7) << 3))];
    }

    float rsacc[4] = {0.f, 0.f, 0.f, 0.f};
    for (int nt = 0; nt < 8; ++nt) {
        __syncthreads();
        #pragma unroll
        for (int i = 0; i < 8; ++i) {
            const int q = i * 256 + t;
            const int row = q >> 5, c16 = (q & 31) * 8;
            const uint4 v = *(const uint4*)&Tb[(nt * 64 + row) * 256 + c16];
            *(uint4*)&shT[row * 256 + (c16 ^ ((row & 7) << 3))] = v;
        }
        __syncthreads();
        #pragma unroll
        for (int ns = 0; ns < 4; ++ns) {
            f32x4 acc = {0.f, 0.f, 0.f, 0.f};
            const int row = ns * 16 + lo;
            #pragma unroll
            for (int kb = 0; kb < 8; ++kb) {
                const u32x4 bfr = *(const u32x4*)&shT[row * 256 + ((kb * 32 + hi * 8) ^ ((row & 7) << 3))];
                mfma_bf16(acc, afr[kb], bfr);
            }
            mfma_fence(acc);
            rsacc[0] += __expf(acc.x); rsacc[1] += __expf(acc.y);
            rsacc[2] += __expf(acc.z); rsacc[3] += __expf(acc.w);
        }
    }
    #pragma unroll
    for (int q = 0; q < 4; ++q) {
        float v = rsacc[q];
        v += __shfl_xor(v, 1); v += __shfl_xor(v, 2);
        v += __shfl_xor(v, 4); v += __shfl_xor(v, 8);
        rsacc[q] = v;
    }
    if (lo == 0) {
        const int m = mb * 64 + w * 16 + hi * 4;
        float* dst = rs + (nq * 4 + b) * N_ + m;
        dst[0] = rsacc[0]; dst[1] = rsacc[1]; dst[2] = rsacc[2]; dst[3] = rsacc[3];
    }
}

// ---------------------------------------------------------------------------
// Pass B (MFMA, flash-style): recompute S tile-by-tile, P = exp(S)*inv[m] in
// registers (bf16-packed), PV-accumulate Yt[c''][n] = sum_m g[c''][m] P[m][n].
// ---------------------------------------------------------------------------
__global__ __launch_bounds__(256) void passB_mfma(
    const u16* __restrict__ phit, const u16* __restrict__ thetat,
    const u16* __restrict__ g, const float* __restrict__ rs,
    u16* __restrict__ Yt)
{
    __shared__ __align__(16) u16 shT[64 * 256];   // theta n-tile (block-constant)
    __shared__ __align__(16) u16 shPm[32 * 256];  // phit m-step tile
    __shared__ __align__(16) u16 shG[64 * 32];    // g c''-tile for m-step
    __shared__ float shInv[32];

    const int t = threadIdx.x, b = blockIdx.z, ch = blockIdx.y, nb = blockIdx.x;
    const u16* Tb = thetat + b * BSTR + nb * 64 * 256;
    const u16* Pb = phit + b * BSTR;
    const u16* Gb = g + b * BSTR + ch * 64 * N_;
    const int lane = t & 63, w = t >> 6, lo = lane & 15, hi = lane >> 4;

    #pragma unroll
    for (int i = 0; i < 8; ++i) {
        const int q = i * 256 + t;
        const int row = q >> 5, c16 = (q & 31) * 8;
        const uint4 v = *(const uint4*)&Tb[row * 256 + c16];
        *(uint4*)&shT[row * 256 + (c16 ^ ((row & 7) << 3))] = v;
    }
    __syncthreads();
    u32x4 bfr[8];
    {
        const int row = w * 16 + lo;
        #pragma unroll
        for (int kb = 0; kb < 8; ++kb)
            bfr[kb] = *(const u32x4*)&shT[row * 256 + ((kb * 32 + hi * 8) ^ ((row & 7) << 3))];
    }

    f32x4 accY[4];
    #pragma unroll
    for (int ct = 0; ct < 4; ++ct) accY[ct] = (f32x4){0.f, 0.f, 0.f, 0.f};

    for (int mt = 0; mt < 64; ++mt) {
        __syncthreads();
        #pragma unroll
        for (int i = 0; i < 4; ++i) {
            const int q = i * 256 + t;
            const int row = q >> 5, c16 = (q & 31) * 8;
            const uint4 v = *(const uint4*)&Pb[(mt * 32 + row) * 256 + c16];
            *(uint4*)&shPm[row * 256 + (c16 ^ ((row & 7) << 3))] = v;
        }
        {
            const int row = t >> 2, qd = t & 3;
            const uint4 v = *(const uint4*)&Gb[row * N_ + mt * 32 + qd * 8];
            const int base = row * 32, m0 = qd * 8, sw = (row & 7) << 2;
            *(uint2*)&shG[base + ((m0    ) ^ sw)] = make_uint2(v.x, v.y);
            *(uint2*)&shG[base + ((m0 + 4) ^ sw)] = make_uint2(v.z, v.w);
        }
        if (t < 32) {
            const float* rp = rs + b * N_ + mt * 32 + t;
            shInv[t] = 1.0f / (rp[0] + rp[8192] + rp[16384] + rp[24576]);
        }
        __syncthreads();

        f32x4 s0 = {0.f, 0.f, 0.f, 0.f}, s1 = {0.f, 0.f, 0.f, 0.f};
        {
            const int row = lo;
            #pragma unroll
            for (int kb = 0; kb < 8; ++kb) {
                const u32x4 a = *(const u32x4*)&shPm[row * 256 + ((kb * 32 + hi * 8) ^ ((row & 7) << 3))];
                mfma_bf16(s0, a, bfr[kb]);
            }
        }
        {
            const int row = 16 + lo;
            #pragma unroll
            for (int kb = 0; kb < 8; ++kb) {
                const u32x4 a = *(const u32x4*)&shPm[row * 256 + ((kb * 32 + hi * 8) ^ ((row & 7) << 3))];
                mfma_bf16(s1, a, bfr[kb]);
            }
        }
        mfma_fence(s0); mfma_fence(s1);

        float p0[4], p1[4];
        #pragma unroll
        for (int q = 0; q < 4; ++q) {
            p0[q] = __expf(s0[q]) * shInv[hi * 4 + q];
            p1[q] = __expf(s1[q]) * shInv[16 + hi * 4 + q];
        }
        u32x4 pf;
        pf[0] = (unsigned)f2bf(p0[0]) | ((unsigned)f2bf(p0[1]) << 16);
        pf[1] = (unsigned)f2bf(p0[2]) | ((unsigned)f2bf(p0[3]) << 16);
        pf[2] = (unsigned)f2bf(p1[0]) | ((unsigned)f2bf(p1[1]) << 16);
        pf[3] = (unsigned)f2bf(p1[2]) | ((unsigned)f2bf(p1[3]) << 16);

        #pragma unroll
        for (int ct = 0; ct < 4; ++ct) {
            const int row = ct * 16 + lo;
            const int sw = (row & 7) << 2, m4 = hi * 4;
            const uint2 a0 = *(const uint2*)&shG[row * 32 + ((m4     ) ^ sw)];
            const uint2 a1 = *(const uint2*)&shG[row * 32 + ((16 + m4) ^ sw)];
            u32x4 gf; gf[0] = a0.x; gf[1] = a0.y; gf[2] = a1.x; gf[3] = a1.y;
            mfma_bf16_vsrc(accY[ct], gf, pf);
        }
    }

    u16* Yb = Yt + b * BSTR;
    #pragma unroll
    for (int ct = 0; ct < 4; ++ct) {
        mfma_fence(accY[ct]);
        const int crow = ch * 64 + ct * 16 + hi * 4;
        const int col  = nb * 64 + w * 16 + lo;
        #pragma unroll
        for (int q = 0; q < 4; ++q)
            Yb[(crow + q) * N_ + col] = f2bf(accY[ct][q]);
    }
}

// ---------------------------------------------------------------------------
// mask_add: out[o][p] += sum_k W_mask[o][k] * Yview[k][p]
// ---------------------------------------------------------------------------
__global__ __launch_bounds__(256) void mask_add_kernel(
    const u16* __restrict__ Yt, const float* __restrict__ Wm,
    float* __restrict__ out)
{
    const int p  = blockIdx.x * 256 + threadIdx.x;
    const int og = blockIdx.y;
    const int b  = blockIdx.z;
    const u16* Yb = Yt + b * BSTR;

    float acc[8] = {};
    for (int k = 0; k < 128; ++k) {
        const float y = bf2f(Yb[k * HW + p]);
        #pragma unroll
        for (int j = 0; j < 8; ++j)
            acc[j] = fmaf(Wm[(og * 8 + j) * 128 + k], y, acc[j]);
    }
    float* ob = out + (size_t)b * C_ * HW;
    #pragma unroll
    for (int j = 0; j < 8; ++j)
        ob[(og * 8 + j) * HW + p] += acc[j];
}

// ---------------------------------------------------------------------------
extern "C" void kernel_launch(void* const* d_in, const int* in_sizes, int n_in,
                              void* d_out, int out_size, void* d_ws, size_t ws_size,
                              hipStream_t stream)
{
    const float* A      = (const float*)d_in[0];
    const float* Bx     = (const float*)d_in[1];
    const float* Wphi   = (const float*)d_in[2];
    const float* Wtheta = (const float*)d_in[3];
    const float* Wg     = (const float*)d_in[4];
    const float* Wab    = (const float*)d_in[5];
    const float* Wmask  = (const float*)d_in[6];
    float* out = (float*)d_out;

    // workspace (~28.6 MB):
    //   ABt [4][4096][512] u16 = 16 MB   (dead after conv_gemm)
    //     Yt  aliases ABt+0     (4 MB, written by passB)
    //     rs  aliases ABt+4MB   (128 KB, written by passA)
    //   Wt  [640][512] u16 = 0.625 MB
    //   phit/thetat/g: 4 MB each
    u16*   ABt    = (u16*)d_ws;
    u16*   Yt     = ABt;                                   // alias (ABt dead)
    float* rs     = (float*)(ABt + 2097152);               // alias at +4 MB
    u16*   Wt     = ABt + 8388608;                         // +16 MB
    u16*   phit   = Wt + 327680;
    u16*   thetat = phit + 4 * BSTR / 2 * 2;               // + 2097152
    u16*   g      = thetat + 2097152;

    prep_w<<<dim3(640), 256, 0, stream>>>(Wphi, Wtheta, Wg, Wab, Wt);

    prep_abt<<<dim3(64, 4), 256, 0, stream>>>(A, Bx, ABt);

    conv_gemm<<<dim3(64, 10, 4), 256, 0, stream>>>(
        Wt, ABt, phit, thetat, g, out);

    passA_mfma<<<dim3(32, 4, 4), 256, 0, stream>>>(phit, thetat, rs);

    passB_mfma<<<dim3(32, 4, 4), 256, 0, stream>>>(phit, thetat, g, rs, Yt);

    mask_add_kernel<<<dim3(16, 32, 4), 256, 0, stream>>>(Yt, Wmask, out);
}